// Round 6
// baseline (2394.614 us; speedup 1.0000x reference)
//
#include <hip/hip_runtime.h>
#include <stdint.h>

// Problem constants
#define TS 64
#define BATCH 1024
#define HID 256
#define IMGD 2048
#define HPAD 272   // h_lds row stride in bf16 units (544 B: 16B-aligned, banks spread)

typedef __bf16 bf16_t;
typedef bf16_t bf16x8 __attribute__((ext_vector_type(8)));
typedef float f32x4 __attribute__((ext_vector_type(4)));

// load 8 consecutive fp32 (16B-aligned) and convert to a bf16x8 MFMA fragment
static __device__ __forceinline__ bf16x8 cvt8(const float* __restrict__ p) {
    const f32x4 a = *reinterpret_cast<const f32x4*>(p);
    const f32x4 b = *reinterpret_cast<const f32x4*>(p + 4);
    bf16x8 r;
    r[0] = (bf16_t)a[0]; r[1] = (bf16_t)a[1]; r[2] = (bf16_t)a[2]; r[3] = (bf16_t)a[3];
    r[4] = (bf16_t)b[0]; r[5] = (bf16_t)b[1]; r[6] = (bf16_t)b[2]; r[7] = (bf16_t)b[3];
    return r;
}
static __device__ __forceinline__ uint16_t f2bf(float f) {
    union { float f; uint32_t i; } c; c.f = f;
    uint32_t i = c.i;
    i += 0x7fffu + ((i >> 16) & 1u);   // RNE
    return (uint16_t)(i >> 16);
}
static __device__ __forceinline__ float sigm(float x) { return 1.f / (1.f + __expf(-x)); }
static __device__ __forceinline__ float tanh_f(float x) { return 1.f - 2.f / (1.f + __expf(2.f * x)); }

// ---------------------------------------------------------------------------
// Single persistent kernel, ZERO inter-block communication.
// 64 blocks x 1024 threads (16 waves). Block g owns batch rows [16g,16g+16)
// and ALL 256 hidden units: wave w owns units [16w,16w+16) x 4 gates, with
// the same per-wave register-resident weight fragments as before (lesson R4:
// all fragment indices compile-time constant; lesson R5: cross-block sync
// through MALL costs ~16k cyc/step -> keep h on-CU).
//
// h exchange: LDS, double-buffered, ONE __syncthreads per step.
//   write: lane owns (batch row j, units ulane..+4) -> ds_write_b64
//   read:  B-frag = h[row j][units kk*32+quad*8..+8] -> ds_read_b128
// WAR safety: step t reads buf[(t-1)&1], writes buf[t&1]; the step t-1
// barrier separates step t-1's reads of buf[t&1] from step t's writes.
// ---------------------------------------------------------------------------
__global__ __launch_bounds__(1024, 4) void lstm_kernel(
    const float* __restrict__ img_feature, const int* __restrict__ caption,
    const float* __restrict__ W_img, const float* __restrict__ b_img,
    const float* __restrict__ emb,
    const float* __restrict__ W_ih, const float* __restrict__ W_hh,
    const float* __restrict__ b_ih, const float* __restrict__ b_hh,
    float* __restrict__ out)
{
    __shared__ __align__(16) uint16_t h_lds[2][16 * HPAD];   // 17.4 KB

    const int g = blockIdx.x;            // batch group 0..63
    const int b0 = g * 16;
    const int wave = threadIdx.x >> 6;   // 0..15 -> unit tile
    const int lane = threadIdx.x & 63;
    const int quad = lane >> 4, j = lane & 15;
    const int uw = wave * 16;            // wave's first unit
    const int ulane = uw + quad * 4;     // this lane's first unit (owns 4)
    const int brow = b0 + j;             // this lane's batch row

    // ---- img prologue: imgv[r] = relu(img_feature[brow] . W_img[ulane+r] + b)
    float imgv[4];
    {
        f32x4 D = {};
        const float* aw = W_img + (size_t)(uw + j) * IMGD + quad * 8;
        const float* bx = img_feature + (size_t)brow * IMGD + quad * 8;
        for (int kk = 0; kk < 64; ++kk) {
            bf16x8 a = cvt8(aw + kk * 32);
            bf16x8 b = cvt8(bx + kk * 32);
            D = __builtin_amdgcn_mfma_f32_16x16x32_bf16(a, b, D, 0, 0, 0);
        }
#pragma unroll
        for (int r = 0; r < 4; ++r) {
            float v = D[r] + b_img[ulane + r];
            imgv[r] = v > 0.f ? v : 0.f;
        }
    }

    // ---- persistent weight A-fragments (compile-time indices ONLY):
    // m = lane&15 = j -> gate row q*HID + uw + j; k = kk*32 + quad*8
    bf16x8 Aih[4][8], Ahh[4][8];
#pragma unroll
    for (int q = 0; q < 4; ++q) {
        const int r = q * HID + uw + j;
        const float* pih = W_ih + (size_t)r * HID + quad * 8;
        const float* phh = W_hh + (size_t)r * HID + quad * 8;
#pragma unroll
        for (int kk = 0; kk < 8; ++kk) {
            Aih[q][kk] = cvt8(pih + kk * 32);
            Ahh[q][kk] = cvt8(phh + kk * 32);
        }
    }
    f32x4 biasv[4];
#pragma unroll
    for (int q = 0; q < 4; ++q)
#pragma unroll
        for (int r = 0; r < 4; ++r)
            biasv[q][r] = b_ih[q * HID + ulane + r] + b_hh[q * HID + ulane + r];

    float cst[4] = {0.f, 0.f, 0.f, 0.f};

    // ---- x B-fragments for t=0: n=j -> batch brow, k = kk*32 + quad*8
    bf16x8 Bx[8], Bxn[8];
    {
        int cap = caption[brow];
        const float* px = emb + (size_t)cap * HID + quad * 8;
#pragma unroll
        for (int kk = 0; kk < 8; ++kk) Bx[kk] = cvt8(px + kk * 32);
    }

    for (int t = 0; t < TS; ++t) {
        f32x4 C[4];
#pragma unroll
        for (int q = 0; q < 4; ++q) C[q] = biasv[q];

        // x_t part
#pragma unroll
        for (int kk = 0; kk < 8; ++kk) {
#pragma unroll
            for (int q = 0; q < 4; ++q)
                C[q] = __builtin_amdgcn_mfma_f32_16x16x32_bf16(Aih[q][kk], Bx[kk], C[q], 0, 0, 0);
        }

        // prefetch next step's embedding row (lands during next step's MFMA)
        {
            int tn = (t + 1 < TS) ? t + 1 : t;
            int cap = caption[tn * BATCH + brow];
            const float* px = emb + (size_t)cap * HID + quad * 8;
#pragma unroll
            for (int kk = 0; kk < 8; ++kk) Bxn[kk] = cvt8(px + kk * 32);
        }

        // h(t-1) part from LDS (on-CU, no cross-block traffic)
        if (t > 0) {
            const uint16_t* hrow = &h_lds[(t - 1) & 1][j * HPAD + quad * 8];
#pragma unroll
            for (int kk = 0; kk < 8; ++kk) {
                bf16x8 H = *reinterpret_cast<const bf16x8*>(hrow + kk * 32);
#pragma unroll
                for (int q = 0; q < 4; ++q)
                    C[q] = __builtin_amdgcn_mfma_f32_16x16x32_bf16(Ahh[q][kk], H, C[q], 0, 0, 0);
            }
        }

        // LSTM cell: lane holds 4 consecutive units x 1 batch row
        float hval[4];
        unsigned long long hpack = 0;
#pragma unroll
        for (int r = 0; r < 4; ++r) {
            float ig = sigm(C[0][r]);
            float fg = sigm(C[1][r]);
            float gg = tanh_f(C[2][r]);
            float og = sigm(C[3][r]);
            float c = fg * cst[r] + ig * gg;
            cst[r] = c;
            float h = og * tanh_f(c);
            hval[r] = h;
            hpack |= ((unsigned long long)f2bf(h)) << (16 * r);
        }

        // publish h(t) to LDS (8B store), then one barrier
        *reinterpret_cast<unsigned long long*>(&h_lds[t & 1][j * HPAD + ulane]) = hpack;
        __syncthreads();

        // out store: coalesced f32x4, off the critical path
        {
            f32x4 o;
#pragma unroll
            for (int r = 0; r < 4; ++r) o[r] = hval[r] + imgv[r];
            *reinterpret_cast<f32x4*>(out + ((size_t)t * BATCH + brow) * HID + ulane) = o;
        }

#pragma unroll
        for (int kk = 0; kk < 8; ++kk) Bx[kk] = Bxn[kk];
    }
}

// ---------------------------------------------------------------------------
extern "C" void kernel_launch(void* const* d_in, const int* in_sizes, int n_in,
                              void* d_out, int out_size, void* d_ws, size_t ws_size,
                              hipStream_t stream) {
    const float* img_feature = (const float*)d_in[0];   // [1024, 2048] fp32
    const int*   caption     = (const int*)d_in[1];     // [64, 1024] int32
    const float* W_img       = (const float*)d_in[2];   // [256, 2048] fp32
    const float* b_img       = (const float*)d_in[3];   // [256] fp32
    const float* emb         = (const float*)d_in[4];   // [32000, 256] fp32
    const float* W_ih        = (const float*)d_in[5];   // [1024, 256] fp32
    const float* W_hh        = (const float*)d_in[6];   // [1024, 256] fp32
    const float* b_ih        = (const float*)d_in[7];   // [1024] fp32
    const float* b_hh        = (const float*)d_in[8];   // [1024] fp32
    float* out = (float*)d_out;                         // [64,1024,256] fp32

    // no workspace, no memset, single launch
    lstm_kernel<<<64, 1024, 0, stream>>>(img_feature, caption, W_img, b_img, emb,
                                         W_ih, W_hh, b_ih, b_hh, out);
}

// Round 7
// 2389.385 us; speedup vs baseline: 1.0022x; 1.0022x over previous
//
#include <hip/hip_runtime.h>
#include <stdint.h>

// Problem constants
#define TS 64
#define BATCH 1024
#define HID 256
#define IMGD 2048
#define HPAD 264   // h_lds row stride in bf16 units (528 B = 132 dw; 4j+2q mod 32 -> 2-way=free)

typedef __bf16 bf16_t;
typedef bf16_t bf16x8 __attribute__((ext_vector_type(8)));
typedef float f32x4 __attribute__((ext_vector_type(4)));

// load 8 consecutive fp32 (16B-aligned) and convert to a bf16x8 MFMA fragment
static __device__ __forceinline__ bf16x8 cvt8(const float* __restrict__ p) {
    const f32x4 a = *reinterpret_cast<const f32x4*>(p);
    const f32x4 b = *reinterpret_cast<const f32x4*>(p + 4);
    bf16x8 r;
    r[0] = (bf16_t)a[0]; r[1] = (bf16_t)a[1]; r[2] = (bf16_t)a[2]; r[3] = (bf16_t)a[3];
    r[4] = (bf16_t)b[0]; r[5] = (bf16_t)b[1]; r[6] = (bf16_t)b[2]; r[7] = (bf16_t)b[3];
    return r;
}
static __device__ __forceinline__ uint16_t f2bf(float f) {
    union { float f; uint32_t i; } c; c.f = f;
    uint32_t i = c.i;
    i += 0x7fffu + ((i >> 16) & 1u);   // RNE
    return (uint16_t)(i >> 16);
}
static __device__ __forceinline__ float sigm(float x) { return 1.f / (1.f + __expf(-x)); }
static __device__ __forceinline__ float tanh_f(float x) { return 1.f - 2.f / (1.f + __expf(2.f * x)); }

// ---------------------------------------------------------------------------
// Single persistent kernel, ZERO inter-block communication.
// 64 blocks x 1024 threads (16 waves). Block g owns batch rows [16g,16g+16)
// and ALL 256 hidden units: wave w owns units [16w,16w+16) x 4 gates.
//
// LESSONS ENCODED:
//  R4: fragment array indices must be compile-time constants (runtime index
//      -> scratch demotion -> 790 MB refetch, measured).
//  R5: cross-block sync through MALL costs ~16k cyc/step -> keep h on-CU.
//  R6: __launch_bounds__(1024,4) made the allocator cap at 64 VGPRs and
//      spill the weights (FETCH 1.99 GB = 65536 thr x 64 steps x ~450 B
//      re-read, measured). Use (1024,1): same per-wave budget as R5's
//      proven-resident (256,1) binary; 4 waves/SIMD x ~460 regs fits 2048.
//
// h exchange: LDS, double-buffered, ONE __syncthreads per step.
// WAR safety: step t reads buf[(t-1)&1] BEFORE the barrier, writes buf[t&1]
// before the barrier; the barrier separates t's reads from t+1's writes.
// ---------------------------------------------------------------------------
__global__ __launch_bounds__(1024, 1) void lstm_kernel(
    const float* __restrict__ img_feature, const int* __restrict__ caption,
    const float* __restrict__ W_img, const float* __restrict__ b_img,
    const float* __restrict__ emb,
    const float* __restrict__ W_ih, const float* __restrict__ W_hh,
    const float* __restrict__ b_ih, const float* __restrict__ b_hh,
    float* __restrict__ out)
{
    __shared__ __align__(16) uint16_t h_lds[2][16 * HPAD];   // 16.5 KB

    const int g = blockIdx.x;            // batch group 0..63
    const int b0 = g * 16;
    const int wave = threadIdx.x >> 6;   // 0..15 -> unit tile
    const int lane = threadIdx.x & 63;
    const int quad = lane >> 4, j = lane & 15;
    const int uw = wave * 16;            // wave's first unit
    const int ulane = uw + quad * 4;     // this lane's first unit (owns 4)
    const int brow = b0 + j;             // this lane's batch row

    // ---- img prologue: imgv[r] = relu(img_feature[brow] . W_img[ulane+r] + b)
    float imgv[4];
    {
        f32x4 D = {};
        const float* aw = W_img + (size_t)(uw + j) * IMGD + quad * 8;
        const float* bx = img_feature + (size_t)brow * IMGD + quad * 8;
        for (int kk = 0; kk < 64; ++kk) {
            bf16x8 a = cvt8(aw + kk * 32);
            bf16x8 b = cvt8(bx + kk * 32);
            D = __builtin_amdgcn_mfma_f32_16x16x32_bf16(a, b, D, 0, 0, 0);
        }
#pragma unroll
        for (int r = 0; r < 4; ++r) {
            float v = D[r] + b_img[ulane + r];
            imgv[r] = v > 0.f ? v : 0.f;
        }
    }

    // ---- persistent weight A-fragments (compile-time indices ONLY):
    // m = lane&15 = j -> gate row q*HID + uw + j; k = kk*32 + quad*8
    bf16x8 Aih[4][8], Ahh[4][8];
#pragma unroll
    for (int q = 0; q < 4; ++q) {
        const int r = q * HID + uw + j;
        const float* pih = W_ih + (size_t)r * HID + quad * 8;
        const float* phh = W_hh + (size_t)r * HID + quad * 8;
#pragma unroll
        for (int kk = 0; kk < 8; ++kk) {
            Aih[q][kk] = cvt8(pih + kk * 32);
            Ahh[q][kk] = cvt8(phh + kk * 32);
        }
    }
    f32x4 biasv[4];
#pragma unroll
    for (int q = 0; q < 4; ++q)
#pragma unroll
        for (int r = 0; r < 4; ++r)
            biasv[q][r] = b_ih[q * HID + ulane + r] + b_hh[q * HID + ulane + r];

    float cst[4] = {0.f, 0.f, 0.f, 0.f};

    // ---- x B-fragments for t=0: n=j -> batch brow, k = kk*32 + quad*8
    bf16x8 Bx[8];
    {
        int cap = caption[brow];
        const float* px = emb + (size_t)cap * HID + quad * 8;
#pragma unroll
        for (int kk = 0; kk < 8; ++kk) Bx[kk] = cvt8(px + kk * 32);
    }

    for (int t = 0; t < TS; ++t) {
        f32x4 C[4];
#pragma unroll
        for (int q = 0; q < 4; ++q) C[q] = biasv[q];

        // x_t part (consumes Bx)
#pragma unroll
        for (int kk = 0; kk < 8; ++kk) {
#pragma unroll
            for (int q = 0; q < 4; ++q)
                C[q] = __builtin_amdgcn_mfma_f32_16x16x32_bf16(Aih[q][kk], Bx[kk], C[q], 0, 0, 0);
        }

        // prefetch next step's embedding row DIRECTLY into Bx (its last use
        // was above; same-register dependence prevents reorder; no consumer
        // until next step -> loads overlap h-MFMA + cell + barrier)
        {
            int tn = (t + 1 < TS) ? t + 1 : t;
            int cap = caption[tn * BATCH + brow];
            const float* px = emb + (size_t)cap * HID + quad * 8;
#pragma unroll
            for (int kk = 0; kk < 8; ++kk) Bx[kk] = cvt8(px + kk * 32);
        }

        // h(t-1) part from LDS (on-CU, no cross-block traffic)
        if (t > 0) {
            const uint16_t* hrow = &h_lds[(t - 1) & 1][j * HPAD + quad * 8];
#pragma unroll
            for (int kk = 0; kk < 8; ++kk) {
                bf16x8 H = *reinterpret_cast<const bf16x8*>(hrow + kk * 32);
#pragma unroll
                for (int q = 0; q < 4; ++q)
                    C[q] = __builtin_amdgcn_mfma_f32_16x16x32_bf16(Ahh[q][kk], H, C[q], 0, 0, 0);
            }
        }

        // LSTM cell: lane holds 4 consecutive units x 1 batch row
        float hval[4];
        unsigned long long hpack = 0;
#pragma unroll
        for (int r = 0; r < 4; ++r) {
            float ig = sigm(C[0][r]);
            float fg = sigm(C[1][r]);
            float gg = tanh_f(C[2][r]);
            float og = sigm(C[3][r]);
            float c = fg * cst[r] + ig * gg;
            cst[r] = c;
            float h = og * tanh_f(c);
            hval[r] = h;
            hpack |= ((unsigned long long)f2bf(h)) << (16 * r);
        }

        // publish h(t) to LDS (8B store), then the step's single barrier
        *reinterpret_cast<unsigned long long*>(&h_lds[t & 1][j * HPAD + ulane]) = hpack;
        __syncthreads();

        // out store: coalesced f32x4, off the critical path
        {
            f32x4 o;
#pragma unroll
            for (int r = 0; r < 4; ++r) o[r] = hval[r] + imgv[r];
            *reinterpret_cast<f32x4*>(out + ((size_t)t * BATCH + brow) * HID + ulane) = o;
        }
    }
}

// ---------------------------------------------------------------------------
extern "C" void kernel_launch(void* const* d_in, const int* in_sizes, int n_in,
                              void* d_out, int out_size, void* d_ws, size_t ws_size,
                              hipStream_t stream) {
    const float* img_feature = (const float*)d_in[0];   // [1024, 2048] fp32
    const int*   caption     = (const int*)d_in[1];     // [64, 1024] int32
    const float* W_img       = (const float*)d_in[2];   // [256, 2048] fp32
    const float* b_img       = (const float*)d_in[3];   // [256] fp32
    const float* emb         = (const float*)d_in[4];   // [32000, 256] fp32
    const float* W_ih        = (const float*)d_in[5];   // [1024, 256] fp32
    const float* W_hh        = (const float*)d_in[6];   // [1024, 256] fp32
    const float* b_ih        = (const float*)d_in[7];   // [1024] fp32
    const float* b_hh        = (const float*)d_in[8];   // [1024] fp32
    float* out = (float*)d_out;                         // [64,1024,256] fp32

    // no workspace, no memset, single launch
    lstm_kernel<<<64, 1024, 0, stream>>>(img_feature, caption, W_img, b_img, emb,
                                         W_ih, W_hh, b_ih, b_hh, out);
}

// Round 8
// 918.408 us; speedup vs baseline: 2.6074x; 2.6017x over previous
//
#include <hip/hip_runtime.h>
#include <stdint.h>

// Problem constants
#define TS 64
#define BATCH 1024
#define HID 256
#define IMGD 2048

typedef __bf16 bf16_t;
typedef bf16_t bf16x8 __attribute__((ext_vector_type(8)));
typedef float f32x4 __attribute__((ext_vector_type(4)));

union U64F2 {
    unsigned long long u[2];
    bf16x8 v;
};

// load 8 consecutive fp32 (16B-aligned) and convert to a bf16x8 MFMA fragment
static __device__ __forceinline__ bf16x8 cvt8(const float* __restrict__ p) {
    const f32x4 a = *reinterpret_cast<const f32x4*>(p);
    const f32x4 b = *reinterpret_cast<const f32x4*>(p + 4);
    bf16x8 r;
    r[0] = (bf16_t)a[0]; r[1] = (bf16_t)a[1]; r[2] = (bf16_t)a[2]; r[3] = (bf16_t)a[3];
    r[4] = (bf16_t)b[0]; r[5] = (bf16_t)b[1]; r[6] = (bf16_t)b[2]; r[7] = (bf16_t)b[3];
    return r;
}
static __device__ __forceinline__ uint16_t f2bf(float f) {
    union { float f; uint32_t i; } c; c.f = f;
    uint32_t i = c.i;
    i += 0x7fffu + ((i >> 16) & 1u);   // RNE
    return (uint16_t)(i >> 16);
}
static __device__ __forceinline__ float sigm(float x) { return 1.f / (1.f + __expf(-x)); }
static __device__ __forceinline__ float tanh_f(float x) { return 1.f - 2.f / (1.f + __expf(2.f * x)); }

// two relaxed agent-scope u64 atomic loads -> one bf16x8 fragment
static __device__ __forceinline__ bf16x8 ld_h16(const unsigned long long* p) {
    U64F2 f;
    f.u[0] = __hip_atomic_load(p,     __ATOMIC_RELAXED, __HIP_MEMORY_SCOPE_AGENT);
    f.u[1] = __hip_atomic_load(p + 1, __ATOMIC_RELAXED, __HIP_MEMORY_SCOPE_AGENT);
    return f.v;
}

// ---------------------------------------------------------------------------
// Persistent fused kernel. 128 blocks x 256 threads.
// Block (p = blk>>2, ch = blk&3) services TWO independent batch-groups
// (rows [16p,16p+16) and [16(p+32),16(p+32)+16)) for unit chunk
// [64ch, 64ch+64). The two groups' phases are interleaved per step so each
// group's cross-CU sync round-trip (flag poll + MALL h-loads) is hidden
// behind the OTHER group's compute (R5 lesson: the RTT itself is ~irreducible;
// R7 lesson: a zero-comm design is register-capacity-impossible).
//
// Weights (shared by both groups) live in registers/AGPRs: 64 bf16x8 frags =
// 256 regs/wave; ALL fragment indices compile-time constants (R4 lesson:
// runtime index -> scratch -> GB-scale refetch).
//
// Sync per group-phase: u64 h stores -> __syncthreads (each wave drains its
// vmcnt before s_barrier -> stores performed at MALL) -> thread0 relaxed
// SIGNED flag store = t+1. Consumer polls 3 peer flags with SIGNED compare
// (0xAAAAAAAA poison is negative -> no memset needed; '<' handles run-ahead).
// ---------------------------------------------------------------------------
__global__ __launch_bounds__(256, 1) void lstm_kernel(
    const float* __restrict__ img_feature, const int* __restrict__ caption,
    const float* __restrict__ W_img, const float* __restrict__ b_img,
    const float* __restrict__ emb,
    const float* __restrict__ W_ih, const float* __restrict__ W_hh,
    const float* __restrict__ b_ih, const float* __restrict__ b_hh,
    unsigned long long* __restrict__ h_buf64,
    int* __restrict__ ctr, float* __restrict__ out)
{
    const int ch = blockIdx.x & 3;        // unit chunk 0..3
    const int p  = blockIdx.x >> 2;       // group-pair id 0..31
    const int u0 = ch * 64;
    const int wv = threadIdx.x >> 6, lane = threadIdx.x & 63;
    const int quad = lane >> 4, j = lane & 15;
    const int uw = u0 + wv * 16;          // wave's first unit
    const int ulane = uw + quad * 4;      // lane's first unit (owns 4)
    const int pr0 = (ch + 1) & 3, pr1 = (ch + 2) & 3, pr2 = (ch + 3) & 3;

    // ---- img prologue for BOTH groups, sharing the W_img fragment loads
    float imgv[2][4];
    {
        f32x4 D0 = {}, D1 = {};
        const float* aw = W_img + (size_t)(uw + j) * IMGD + quad * 8;
        const float* bx0 = img_feature + (size_t)(p * 16 + j) * IMGD + quad * 8;
        const float* bx1 = img_feature + (size_t)((p + 32) * 16 + j) * IMGD + quad * 8;
        for (int kk = 0; kk < 64; ++kk) {
            bf16x8 a  = cvt8(aw + kk * 32);
            bf16x8 v0 = cvt8(bx0 + kk * 32);
            bf16x8 v1 = cvt8(bx1 + kk * 32);
            D0 = __builtin_amdgcn_mfma_f32_16x16x32_bf16(a, v0, D0, 0, 0, 0);
            D1 = __builtin_amdgcn_mfma_f32_16x16x32_bf16(a, v1, D1, 0, 0, 0);
        }
#pragma unroll
        for (int r = 0; r < 4; ++r) {
            float bi = b_img[ulane + r];
            float v0 = D0[r] + bi, v1 = D1[r] + bi;
            imgv[0][r] = v0 > 0.f ? v0 : 0.f;
            imgv[1][r] = v1 > 0.f ? v1 : 0.f;
        }
    }

    // ---- persistent weight A-fragments (compile-time indices ONLY)
    bf16x8 Aih[4][8], Ahh[4][8];
#pragma unroll
    for (int q = 0; q < 4; ++q) {
        const int r = q * HID + uw + j;
        const float* pih = W_ih + (size_t)r * HID + quad * 8;
        const float* phh = W_hh + (size_t)r * HID + quad * 8;
#pragma unroll
        for (int kk = 0; kk < 8; ++kk) {
            Aih[q][kk] = cvt8(pih + kk * 32);
            Ahh[q][kk] = cvt8(phh + kk * 32);
        }
    }
    f32x4 biasv[4];
#pragma unroll
    for (int q = 0; q < 4; ++q)
#pragma unroll
        for (int r = 0; r < 4; ++r)
            biasv[q][r] = b_ih[q * HID + ulane + r] + b_hh[q * HID + ulane + r];

    float cst[2][4] = {};

    // ---- x B-fragments for t=0 for both groups
    bf16x8 Bx[2][8];
#pragma unroll
    for (int gi = 0; gi < 2; ++gi) {
        const int browg = (p + 32 * gi) * 16 + j;
        int cap = caption[browg];
        const float* px = emb + (size_t)cap * HID + quad * 8;
#pragma unroll
        for (int kk = 0; kk < 8; ++kk) Bx[gi][kk] = cvt8(px + kk * 32);
    }

    for (int t = 0; t < TS; ++t) {
#pragma unroll
        for (int gi = 0; gi < 2; ++gi) {
            const int g = p + 32 * gi;        // batch group
            const int browg = g * 16 + j;     // lane's batch row
            int* flags = ctr + g * 16;        // this group's 64B flag line

            f32x4 C[4];
#pragma unroll
            for (int q = 0; q < 4; ++q) C[q] = biasv[q];

            // x_t part (consumes Bx[gi])
#pragma unroll
            for (int kk = 0; kk < 8; ++kk) {
#pragma unroll
                for (int q = 0; q < 4; ++q)
                    C[q] = __builtin_amdgcn_mfma_f32_16x16x32_bf16(Aih[q][kk], Bx[gi][kk], C[q], 0, 0, 0);
            }

            // prefetch next step's embedding row into Bx[gi]
            {
                int tn = (t + 1 < TS) ? t + 1 : t;
                int cap = caption[tn * BATCH + browg];
                const float* px = emb + (size_t)cap * HID + quad * 8;
#pragma unroll
                for (int kk = 0; kk < 8; ++kk) Bx[gi][kk] = cvt8(px + kk * 32);
            }

            if (t > 0) {
                // poll 3 peer flags (signed: poison 0xAA.. is negative)
                int f0, f1, f2;
                do {
                    f0 = __hip_atomic_load(flags + pr0, __ATOMIC_RELAXED, __HIP_MEMORY_SCOPE_AGENT);
                    f1 = __hip_atomic_load(flags + pr1, __ATOMIC_RELAXED, __HIP_MEMORY_SCOPE_AGENT);
                    f2 = __hip_atomic_load(flags + pr2, __ATOMIC_RELAXED, __HIP_MEMORY_SCOPE_AGENT);
                } while (f0 < t || f1 < t || f2 < t);

                const unsigned long long* hrow = h_buf64
                    + (size_t)((t - 1) & 1) * (BATCH * HID / 4)
                    + (((size_t)browg * HID) >> 2);

                bf16x8 Hall[8];
#pragma unroll
                for (int kk = 0; kk < 8; ++kk)
                    Hall[kk] = ld_h16(hrow + kk * 8 + quad * 2);

#pragma unroll
                for (int kk = 0; kk < 8; ++kk) {
#pragma unroll
                    for (int q = 0; q < 4; ++q)
                        C[q] = __builtin_amdgcn_mfma_f32_16x16x32_bf16(Ahh[q][kk], Hall[kk], C[q], 0, 0, 0);
                }
            }

            // LSTM cell: lane holds 4 consecutive units x 1 batch row
            float hval[4];
            unsigned long long hpack = 0;
#pragma unroll
            for (int r = 0; r < 4; ++r) {
                float ig = sigm(C[0][r]);
                float fg = sigm(C[1][r]);
                float gg = tanh_f(C[2][r]);
                float og = sigm(C[3][r]);
                float c = fg * cst[gi][r] + ig * gg;
                cst[gi][r] = c;
                float h = og * tanh_f(c);
                hval[r] = h;
                hpack |= ((unsigned long long)f2bf(h)) << (16 * r);
            }

            // publish h(t) for this group
            {
                unsigned long long* hw = h_buf64 + (size_t)(t & 1) * (BATCH * HID / 4);
                __hip_atomic_store(hw + (((size_t)browg * HID + ulane) >> 2), hpack,
                                   __ATOMIC_RELAXED, __HIP_MEMORY_SCOPE_AGENT);
            }

            __syncthreads();   // all waves drain vmcnt -> h stores performed
            if (threadIdx.x == 0)
                __hip_atomic_store(flags + ch, t + 1,
                                   __ATOMIC_RELAXED, __HIP_MEMORY_SCOPE_AGENT);

            // out store: coalesced f32x4, off the critical path
            {
                f32x4 o;
#pragma unroll
                for (int r = 0; r < 4; ++r) o[r] = hval[r] + imgv[gi][r];
                *reinterpret_cast<f32x4*>(out + ((size_t)t * BATCH + browg) * HID + ulane) = o;
            }
        }
    }
}

// ---------------------------------------------------------------------------
extern "C" void kernel_launch(void* const* d_in, const int* in_sizes, int n_in,
                              void* d_out, int out_size, void* d_ws, size_t ws_size,
                              hipStream_t stream) {
    const float* img_feature = (const float*)d_in[0];   // [1024, 2048] fp32
    const int*   caption     = (const int*)d_in[1];     // [64, 1024] int32
    const float* W_img       = (const float*)d_in[2];   // [256, 2048] fp32
    const float* b_img       = (const float*)d_in[3];   // [256] fp32
    const float* emb         = (const float*)d_in[4];   // [32000, 256] fp32
    const float* W_ih        = (const float*)d_in[5];   // [1024, 256] fp32
    const float* W_hh        = (const float*)d_in[6];   // [1024, 256] fp32
    const float* b_ih        = (const float*)d_in[7];   // [1024] fp32
    const float* b_hh        = (const float*)d_in[8];   // [1024] fp32
    float* out = (float*)d_out;                         // [64,1024,256] fp32

    uint8_t* ws = (uint8_t*)d_ws;
    unsigned long long* h_buf64 = (unsigned long long*)ws;   // 2 x 512KB bf16 h
    int* ctr = (int*)(ws + (1u << 20));                      // 64 x 64B flag lines
    // no memset needed: flags use signed compare; 0xAAAAAAAA poison < 0

    lstm_kernel<<<128, 256, 0, stream>>>(img_feature, caption, W_img, b_img, emb,
                                         W_ih, W_hh, b_ih, b_hh, h_buf64, ctr, out);
}